// Round 3
// baseline (7738.913 us; speedup 1.0000x reference)
//
#include <hip/hip_runtime.h>

// ---------------------------------------------------------------------------
// LSTM LM: logp = log_softmax(scan_LSTM(emb[seq] @ W_ih^T + b) @ W_out^T + b_out)
// T=2048, H=1024, E=1024, V=32000.  ALL inputs/outputs are float32 (reference
// dtype).  Internally: GEMMs run bf16 MFMA (inputs cast once), the sequential
// scan runs fp32 (where rounding error would compound over 2048 steps).
// ---------------------------------------------------------------------------

typedef __attribute__((ext_vector_type(8))) short short8;
typedef __attribute__((ext_vector_type(4))) float f32x4;
typedef __attribute__((ext_vector_type(4))) int i32x4;
typedef __attribute__((ext_vector_type(4))) unsigned short u16x4;

__device__ __forceinline__ float bf2f(unsigned short u) {
    unsigned int x = ((unsigned int)u) << 16;
    return __builtin_bit_cast(float, x);
}
__device__ __forceinline__ unsigned short f2bf(float f) {
    unsigned int x = __builtin_bit_cast(unsigned int, f);
    x += 0x7FFFu + ((x >> 16) & 1u);   // round-to-nearest-even
    return (unsigned short)(x >> 16);
}

// ---------------------------------------------------------------------------
// fp32 -> bf16 cast, 4 elems/thread (n4 = n/4, n % 4 == 0)
// ---------------------------------------------------------------------------
__global__ __launch_bounds__(256) void cast_f2b(
    const float* __restrict__ src, unsigned short* __restrict__ dst, int n4)
{
    int i = blockIdx.x * 256 + threadIdx.x;
    if (i < n4) {
        f32x4 v = ((const f32x4*)src)[i];
        u16x4 o;
        o.x = f2bf(v.x); o.y = f2bf(v.y); o.z = f2bf(v.z); o.w = f2bf(v.w);
        ((u16x4*)dst)[i] = o;
    }
}

// ---------------------------------------------------------------------------
// xbf[t][:] = bf16(emb[seq[t]][:])   (one block per t, 4 elems/thread, E=1024)
// ---------------------------------------------------------------------------
__global__ __launch_bounds__(256) void gather_cast(
    const int* __restrict__ seq, const float* __restrict__ emb,
    unsigned short* __restrict__ xbf)
{
    int t = blockIdx.x, i = threadIdx.x;
    const f32x4* src = (const f32x4*)(emb + (size_t)seq[t] * 1024);
    f32x4 v = src[i];
    u16x4 o;
    o.x = f2bf(v.x); o.y = f2bf(v.y); o.z = f2bf(v.z); o.w = f2bf(v.w);
    ((u16x4*)(xbf + (size_t)t * 1024))[i] = o;
}

// ---------------------------------------------------------------------------
// hpair[2][1024]: 64-bit (tag<<32 | f32-bits-of-h) transport slots.
// parity-0 prefilled with (tag=0, h0); parity-1 with invalid tag.
// ---------------------------------------------------------------------------
__global__ void init_h(const float* __restrict__ h0,
                       unsigned long long* __restrict__ hpair)
{
    int i = blockIdx.x * 256 + threadIdx.x;
    if (i < 1024) {
        hpair[i] = (unsigned long long)__builtin_bit_cast(unsigned int, h0[i]);
        hpair[1024 + i] = 0xFFFFFFFF00000000ull;
    }
}

// ---------------------------------------------------------------------------
// GEMM: C[M,N](fp32) = A[M,K] @ B[N,K]^T (+ bias0[n] + bias1[n]).  A,B bf16.
// 64x64 tile, BK=32, 256 thr = 4 waves; wave w owns C rows [16w,16w+16).
// mfma_f32_16x16x32_bf16: A-frag lane: row=lane&15, k=(lane>>4)*8+j
//                         B-frag (B^T): same pattern on B rows (= C cols)
//                         C/D: col=lane&15, row=(lane>>4)*4+reg  [m89/m91]
// ---------------------------------------------------------------------------
__global__ __launch_bounds__(256) void gemm_bt(
    const unsigned short* __restrict__ A, const unsigned short* __restrict__ B,
    const float* __restrict__ bias0, const float* __restrict__ bias1,
    float* __restrict__ C, int K, int ldc)
{
    __shared__ __align__(16) unsigned short As[64 * 40];  // +8 pad (2-way max: free)
    __shared__ __align__(16) unsigned short Bs[64 * 40];

    const int tid = threadIdx.x;
    const int m0 = blockIdx.y << 6, n0 = blockIdx.x << 6;
    const int wave = tid >> 6, lane = tid & 63, q = lane >> 4, l = lane & 15;

    f32x4 acc[4];
#pragma unroll
    for (int j = 0; j < 4; j++) acc[j] = (f32x4){0.f, 0.f, 0.f, 0.f};

    const int arow = tid >> 2;          // 0..63
    const int ach  = (tid & 3) * 8;     // 8-bf16 chunk within BK=32

    for (int k0 = 0; k0 < K; k0 += 32) {
        __syncthreads();
        i32x4 av = *(const i32x4*)(A + (size_t)(m0 + arow) * K + k0 + ach);
        i32x4 bv = *(const i32x4*)(B + (size_t)(n0 + arow) * K + k0 + ach);
        *(i32x4*)(&As[arow * 40 + ach]) = av;
        *(i32x4*)(&Bs[arow * 40 + ach]) = bv;
        __syncthreads();
        short8 a = *(const short8*)(&As[(wave * 16 + l) * 40 + q * 8]);
#pragma unroll
        for (int j = 0; j < 4; j++) {
            short8 b = *(const short8*)(&Bs[(j * 16 + l) * 40 + q * 8]);
            acc[j] = __builtin_amdgcn_mfma_f32_16x16x32_bf16(a, b, acc[j], 0, 0, 0);
        }
    }

#pragma unroll
    for (int j = 0; j < 4; j++) {
        int col = n0 + j * 16 + l;
        float bias = 0.f;
        if (bias0) bias += bias0[col];
        if (bias1) bias += bias1[col];
        int row0 = m0 + wave * 16 + q * 4;
#pragma unroll
        for (int r = 0; r < 4; r++)
            C[(size_t)(row0 + r) * ldc + col] = acc[j][r] + bias;
    }
}

// ---------------------------------------------------------------------------
// Persistent LSTM scan. 128 WGs x 512 thr (co-resident; 8 waves/WG).
// WG blk owns units j in [8*blk, 8*blk+8).  Thread (u=tid>>6, s=tid&63) does
// 4-gate partial dots for unit u over h[16s..16s+16); its W_hh slice is
// w[4][16] = 64 floats, fully register-resident (prev round's w[4][32]=128
// floats exceeded the 108 allocated VGPRs -> spilled; per-step weight
// re-streaming was a main cost).  Unit u's 64 threads are exactly one wave
// -> reduction is a pure 64-lane shfl tree, owner = lane 0.
//
// Rotation (k + (s>>1)) & 15 on the 16-word slice keeps LDS dot reads
// bank-conflict-free (even lanes occupy banks 0..15, odd lanes 16..31;
// s>>1 spreads each half over its 16 banks with 2-way aliasing = free).
//
// Transport: FUSED (tag, h) 64-bit slots, one per unit, double-buffered by
// step parity.  Producer: ONE relaxed agent-scope 8B atomic store (single-
// copy atomic -> tag never visible without its h; no drain, no flag, no
// fence).  Consumer: polls its 2 slots with BOTH loads issued before either
// check (one LLC round trip per poll iteration; the previous per-slot
// load-then-check chain serialized 4 RTs).  Exact-match (== t) is safe:
// a tag t+2 overwrite of a parity slot requires every WG to have posted
// t+1, which (the t+1 value is computed from the tag-t reads) requires
// every WG to have consumed tag t.  Skew <= 1 by data dependency.
//
// LDS h-staging double-buffered by parity -> ONE barrier per step.
// Cross-step LDS WAR: a thread staging lh[t&1] at step t+2 has passed
// barrier(t+1), which all threads reach only after their step-t dot. Safe.
// ---------------------------------------------------------------------------
#define NWG 128
__global__ __launch_bounds__(512, 1) void lstm_scan(
    const float* __restrict__ Whh, const float* __restrict__ xg,
    const float* __restrict__ c0, unsigned long long* __restrict__ hpair,
    unsigned short* __restrict__ hs,
    float* __restrict__ outHT, float* __restrict__ outCT, int T)
{
    __shared__ float lh[2][1024];
    const int tid = threadIdx.x, blk = blockIdx.x;
    const int u = tid >> 6, s = tid & 63;
    const int j = blk * 8 + u;
    const int rot = (s >> 1) & 15;

    // stationary weights: w_g[k] = W_hh[g*1024+j][16*s + ((k+rot)&15)]
    float w0[16], w1[16], w2[16], w3[16];
    {
        const float* wr0 = Whh + ((size_t)(0 * 1024 + j)) * 1024 + s * 16;
        const float* wr1 = Whh + ((size_t)(1 * 1024 + j)) * 1024 + s * 16;
        const float* wr2 = Whh + ((size_t)(2 * 1024 + j)) * 1024 + s * 16;
        const float* wr3 = Whh + ((size_t)(3 * 1024 + j)) * 1024 + s * 16;
#pragma unroll
        for (int k = 0; k < 16; k++) {
            int idx = (k + rot) & 15;
            w0[k] = wr0[idx]; w1[k] = wr1[idx];
            w2[k] = wr2[idx]; w3[k] = wr3[idx];
        }
    }

    const bool owner = (s == 0);
    float cst = owner ? c0[j] : 0.f;

    for (int t = 0; t < T; t++) {
        // xg loads are independent of h: issue BEFORE the poll so the HBM
        // latency overlaps the wait for the previous step's producers.
        float xgi = 0.f, xgf = 0.f, xgg = 0.f, xgo = 0.f;
        if (owner) {
            const float* xp = xg + (size_t)t * 4096 + j;
            xgi = xp[0]; xgf = xp[1024]; xgg = xp[2048]; xgo = xp[3072];
        }

        // poll fused (tag,h) slots; both loads in flight before either check.
        {
            const unsigned long long* hb = hpair + (size_t)(t & 1) * 1024;
            const unsigned int want = (unsigned int)t;
            unsigned long long v0, v1;
            for (;;) {
                v0 = __hip_atomic_load(hb + tid, __ATOMIC_RELAXED,
                                       __HIP_MEMORY_SCOPE_AGENT);
                v1 = __hip_atomic_load(hb + tid + 512, __ATOMIC_RELAXED,
                                       __HIP_MEMORY_SCOPE_AGENT);
                if (((unsigned int)(v0 >> 32) == want) &
                    ((unsigned int)(v1 >> 32) == want)) break;
            }
            lh[t & 1][tid]       = __builtin_bit_cast(float, (unsigned int)v0);
            lh[t & 1][tid + 512] = __builtin_bit_cast(float, (unsigned int)v1);
        }
        __syncthreads();   // LDS stage complete (the only barrier per step)

        float a0 = 0.f, a1 = 0.f, a2 = 0.f, a3 = 0.f;
        const float* lhp = &lh[t & 1][s * 16];
#pragma unroll
        for (int k = 0; k < 16; k++) {
            float hk = lhp[(k + rot) & 15];
            a0 += w0[k] * hk; a1 += w1[k] * hk;
            a2 += w2[k] * hk; a3 += w3[k] * hk;
        }
#pragma unroll
        for (int d = 32; d; d >>= 1) {
            a0 += __shfl_down(a0, d, 64); a1 += __shfl_down(a1, d, 64);
            a2 += __shfl_down(a2, d, 64); a3 += __shfl_down(a3, d, 64);
        }

        if (owner) {
            float gi = xgi + a0, gf = xgf + a1, gg = xgg + a2, go = xgo + a3;
            float iv = 1.f / (1.f + __expf(-gi));
            float fv = 1.f / (1.f + __expf(-gf));
            float gv = tanhf(gg);
            float ov = 1.f / (1.f + __expf(-go));
            cst = fv * cst + iv * gv;
            float hv = ov * tanhf(cst);
            unsigned long long pv =
                ((unsigned long long)(unsigned int)(t + 1) << 32) |
                (unsigned long long)__builtin_bit_cast(unsigned int, hv);
            __hip_atomic_store(&hpair[(size_t)((t + 1) & 1) * 1024 + j], pv,
                               __ATOMIC_RELAXED, __HIP_MEMORY_SCOPE_AGENT);
            // hs only consumed by the next kernel: off the critical path.
            hs[(size_t)t * 1024 + j] = f2bf(hv);
            if (t == T - 1) { outHT[j] = hv; outCT[j] = cst; }
        }
        // no second barrier: LDS is parity double-buffered (see header proof)
    }
}

// ---------------------------------------------------------------------------
// In-place row log_softmax, fp32, V=32000. Two passes; pass 2 re-reads the
// L2-hot row. One WG (256 thr) per row, f32x4 vectorized (V/4 = 8000).
// ---------------------------------------------------------------------------
__global__ __launch_bounds__(256) void logsoftmax_rows(float* __restrict__ out, int V)
{
    __shared__ float redm[4], reds[4];
    const int tid = threadIdx.x;
    float* base = out + (size_t)blockIdx.x * V;
    const int n4 = V >> 2;

    float m = -3.0e38f, ssum = 0.f;
    for (int i = tid; i < n4; i += 256) {
        f32x4 v = ((const f32x4*)base)[i];
#pragma unroll
        for (int jj = 0; jj < 4; jj++) {
            float x = v[jj];
            if (x > m) { ssum = ssum * __expf(m - x) + 1.f; m = x; }
            else       { ssum += __expf(x - m); }
        }
    }
#pragma unroll
    for (int d = 32; d; d >>= 1) {
        float om = __shfl_down(m, d, 64);
        float os = __shfl_down(ssum, d, 64);
        float M = fmaxf(m, om);
        ssum = ssum * __expf(m - M) + os * __expf(om - M);
        m = M;
    }
    if ((tid & 63) == 0) { redm[tid >> 6] = m; reds[tid >> 6] = ssum; }
    __syncthreads();
    float M = fmaxf(fmaxf(redm[0], redm[1]), fmaxf(redm[2], redm[3]));
    float S = reds[0] * __expf(redm[0] - M) + reds[1] * __expf(redm[1] - M) +
              reds[2] * __expf(redm[2] - M) + reds[3] * __expf(redm[3] - M);
    float lse = M + logf(S);
    for (int i = tid; i < n4; i += 256) {
        f32x4 v = ((const f32x4*)base)[i];
        v.x -= lse; v.y -= lse; v.z -= lse; v.w -= lse;
        ((f32x4*)base)[i] = v;
    }
}

// ---------------------------------------------------------------------------
extern "C" void kernel_launch(void* const* d_in, const int* in_sizes, int n_in,
                              void* d_out, int out_size, void* d_ws, size_t ws_size,
                              hipStream_t stream)
{
    const int*   seq   = (const int*)d_in[0];
    const float* h0    = (const float*)d_in[1];
    const float* c0    = (const float*)d_in[2];
    const float* emb   = (const float*)d_in[3];
    const float* W_ih  = (const float*)d_in[4];
    const float* W_hh  = (const float*)d_in[5];
    const float* b_ih  = (const float*)d_in[6];
    const float* b_hh  = (const float*)d_in[7];
    const float* W_out = (const float*)d_in[8];
    const float* b_out = (const float*)d_in[9];

    const int T = 2048, H = 1024, V = 32000, G4 = 4096;

    // workspace layout (all regions fully written before read)
    char* ws = (char*)d_ws;
    float*          xg     = (float*)ws;                           // 33,554,432 B
    unsigned short* Woutb  = (unsigned short*)(ws + 33554432);     // 65,536,000 B
    unsigned short* Wihb   = (unsigned short*)(ws + 99090432);     //  8,388,608 B
    unsigned short* xbf    = (unsigned short*)(ws + 107479040);    //  4,194,304 B
    unsigned short* hs     = (unsigned short*)(ws + 111673344);    //  4,194,304 B
    unsigned long long* hpair = (unsigned long long*)(ws + 115867648); // 16,384 B

    float* outp  = (float*)d_out;
    float* outHT = outp + (size_t)T * V;
    float* outCT = outHT + H;

    init_h<<<4, 256, 0, stream>>>(h0, hpair);
    cast_f2b<<<(G4 * 1024 / 4 + 255) / 256, 256, 0, stream>>>(W_ih, Wihb, G4 * 1024 / 4);
    cast_f2b<<<(V * 1024 / 4 + 255) / 256, 256, 0, stream>>>(W_out, Woutb, V * 1024 / 4);
    gather_cast<<<T, 256, 0, stream>>>(seq, emb, xbf);

    // xg[T,4H] = xbf @ Wihb^T + (b_ih + b_hh), fp32
    gemm_bt<<<dim3(G4 / 64, T / 64), 256, 0, stream>>>(
        xbf, Wihb, b_ih, b_hh, xg, 1024, G4);

    // sequential scan -> hs[T,H] bf16, hT/cT fp32
    lstm_scan<<<NWG, 512, 0, stream>>>(W_hh, xg, c0, hpair, hs, outHT, outCT, T);

    // scores[T,V] = hs @ Woutb^T + b_out, fp32 directly into d_out
    gemm_bt<<<dim3(V / 64, T / 64), 256, 0, stream>>>(
        hs, Woutb, b_out, nullptr, outp, 1024, V);

    // in-place log_softmax per row
    logsoftmax_rows<<<T, 256, 0, stream>>>(outp, V);
}